// Round 4
// baseline (107.664 us; speedup 1.0000x reference)
//
#include <hip/hip_runtime.h>
#include <stdint.h>

typedef float  f32x4  __attribute__((ext_vector_type(4)));
typedef __bf16 bf16x8 __attribute__((ext_vector_type(8)));
typedef __bf16 bf16x4 __attribute__((ext_vector_type(4)));

#define N_ 256
#define C_ 512
#define H_ 64
#define RS_ 32768  // row stride in transposed tensors: H_*C_ elements

__device__ __forceinline__ uint32_t pack_bf16x2(float a, float b) {
  const uint16_t ua = __builtin_bit_cast(uint16_t, (__bf16)a);
  const uint16_t ub = __builtin_bit_cast(uint16_t, (__bf16)b);
  return (uint32_t)ua | ((uint32_t)ub << 16);
}

// ---------------------------------------------------------------------------
// Prep: (P, 512c, 64h) fp32 -> (P, 64h, 512c) bf16 for x, w1, w2.
// Block = (c-half, p): reads 64 KB (256c x 64h), writes 32 KB as 512 B
// contiguous segments (per-h rows of the half). LDS stores h-PAIRS packed
// in u32: tile[c][hm], row stride 33 words (phase-2 reads ~8-way, hidden).
// Block (0,0) also zeroes the BN stat accumulators.
// ---------------------------------------------------------------------------
__global__ __launch_bounds__(256) void k_prep(const float* __restrict__ x,
                                              const float* __restrict__ w1,
                                              const float* __restrict__ w2,
                                              __bf16* __restrict__ xT,
                                              __bf16* __restrict__ w1T,
                                              __bf16* __restrict__ w2T,
                                              float* __restrict__ stats) {
  __shared__ uint32_t tile[256][33];
  const int t  = threadIdx.x;
  const int by = blockIdx.y;
  if (by == 0 && blockIdx.x == 0) {
#pragma unroll
    for (int i = 0; i < 8; ++i) stats[i * 256 + t] = 0.f;  // sum1,sq1,sum2,sq2
  }
  const float* src;
  __bf16* dst;
  int p;
  if (by < 256)      { src = x;  dst = xT;  p = by; }
  else if (by < 768) { src = w1; dst = w1T; p = by - 256; }
  else               { src = w2; dst = w2T; p = by - 768; }
  const int ch0 = blockIdx.x * 256;
  const float* sbase = src + ((size_t)p * 512 + ch0) * 64;

  // phase 1: load fp32 (c-rows of h), convert, pack h-pairs into LDS
#pragma unroll
  for (int j = 0; j < 16; ++j) {
    const int fidx = j * 256 + t;
    const int c = fidx >> 4, hq = fidx & 15;
    const float4 v = *reinterpret_cast<const float4*>(sbase + c * 64 + hq * 4);
    tile[c][hq * 2]     = pack_bf16x2(v.x, v.y);
    tile[c][hq * 2 + 1] = pack_bf16x2(v.z, v.w);
  }
  __syncthreads();

  // phase 2: gather 8 consecutive c for one h, store 16 B chunks.
  // lanes: cb = l&31 (c-chunks), h = upper bits -> 512 B global segments.
  __bf16* dbase = dst + (size_t)p * RS_ + ch0;
#pragma unroll
  for (int j = 0; j < 8; ++j) {
    const int ci = j * 256 + t;
    const int cb = ci & 31, h = ci >> 5;
    const int hm = h >> 1;
    const bool odd = (h & 1) != 0;
    uint32_t W[8];
#pragma unroll
    for (int i = 0; i < 8; ++i) W[i] = tile[cb * 8 + i][hm];
    uint4 o;
    uint32_t* op = reinterpret_cast<uint32_t*>(&o);
#pragma unroll
    for (int k = 0; k < 4; ++k) {
      const uint32_t wa = W[2 * k], wb = W[2 * k + 1];
      op[k] = odd ? ((wa >> 16) | (wb & 0xFFFF0000u))
                  : ((wa & 0xFFFFu) | (wb << 16));
    }
    *reinterpret_cast<uint4*>(dbase + (size_t)h * 512 + cb * 8) = o;
  }
}

// ---------------------------------------------------------------------------
// Batched NT GEMM: per h, C[256][512] = A[256][512] * B[512][512]^T  (bf16)
// Layouts: A (N,H,C), B (O,H,C), Co (N,H,C) -- row stride RS_=32768.
// 128x128 tile, 4 waves (2x2), BK=64, mfma_f32_16x16x32_bf16.
// XCD-aware swizzle: 512 blocks, each XCD owns 8 complete h slices.
// 2-phase double-buffered LDS staging; chunk-XOR swizzle via pre-swizzled
// global source (linear LDS dest). Epilogue: bf16 C + sum/sumsq atomics.
// BN_A: A gets y = relu(a1[k]*a + c1[k]) computed on the fly from sum1/sq1.
// ---------------------------------------------------------------------------
template <bool BN_A>
__global__ __launch_bounds__(256, 2) void k_gemm(
    const __bf16* __restrict__ A,
    const __bf16* __restrict__ B,
    __bf16* __restrict__ Co,
    const float* __restrict__ sum_in, const float* __restrict__ sq_in,
    const float* __restrict__ g, const float* __restrict__ bb,
    float* __restrict__ sum_out, float* __restrict__ sq_out) {
  const int wkid = (blockIdx.x & 7) * 64 + (blockIdx.x >> 3);
  const int h  = wkid >> 3;
  const int tm = (wkid >> 2) & 1, tn = wkid & 3;
  const int m0 = tm * 128, n0 = tn * 128;
  const __bf16* Ah = A + (size_t)m0 * RS_ + (size_t)h * C_;
  const __bf16* Bh = B + (size_t)n0 * RS_ + (size_t)h * C_;
  __shared__ __bf16 As[2][128 * 64];
  __shared__ __bf16 Bs[2][128 * 64];
  __shared__ float a_lds[512], c_lds[512];
  const int tid  = threadIdx.x;
  const int lane = tid & 63, wid = tid >> 6;
  const int wr = wid >> 1, wc = wid & 1;
  const int lrow8 = lane >> 3;
  const int swz   = (lane & 7) ^ lrow8;

  if (BN_A) {
#pragma unroll
    for (int ch = tid; ch < 512; ch += 256) {
      const float m    = sum_in[ch] * (1.f / 16384.f);
      const float var  = fmaxf(0.f, sq_in[ch] * (1.f / 16384.f) - m * m);
      const float aa   = g[ch] * rsqrtf(var + 1e-5f);
      a_lds[ch] = aa;
      c_lds[ch] = bb[ch] - m * aa;
    }
    __syncthreads();
  }

  auto stage_b = [&](int buf, int kt) {
#pragma unroll
    for (int i = 0; i < 4; ++i) {
      const int rbase = wid * 32 + i * 8;
      const __bf16* gb = Bh + (size_t)(rbase + lrow8) * RS_ + kt * 64 + swz * 8;
      __builtin_amdgcn_global_load_lds(
          (const __attribute__((address_space(1))) void*)gb,
          (__attribute__((address_space(3))) void*)(&Bs[buf][rbase * 64]), 16, 0, 0);
    }
  };
  auto stage_a = [&](int buf, int kt) {
#pragma unroll
    for (int i = 0; i < 4; ++i) {
      const int rbase = wid * 32 + i * 8;
      const __bf16* ga = Ah + (size_t)(rbase + lrow8) * RS_ + kt * 64 + swz * 8;
      __builtin_amdgcn_global_load_lds(
          (const __attribute__((address_space(1))) void*)ga,
          (__attribute__((address_space(3))) void*)(&As[buf][rbase * 64]), 16, 0, 0);
    }
  };
  const int lr32 = tid >> 3, cch = tid & 7;
  auto load_a = [&](bf16x8* v, int kt) {
#pragma unroll
    for (int i = 0; i < 4; ++i)
      v[i] = *reinterpret_cast<const bf16x8*>(
          Ah + (size_t)(i * 32 + lr32) * RS_ + kt * 64 + cch * 8);
  };
  auto bn_write = [&](const bf16x8* v, int buf, int kt) {
    const int cg = kt * 64 + cch * 8;
    const f32x4 s0 = *reinterpret_cast<const f32x4*>(&a_lds[cg]);
    const f32x4 s1 = *reinterpret_cast<const f32x4*>(&a_lds[cg + 4]);
    const f32x4 h0 = *reinterpret_cast<const f32x4*>(&c_lds[cg]);
    const f32x4 h1 = *reinterpret_cast<const f32x4*>(&c_lds[cg + 4]);
#pragma unroll
    for (int i = 0; i < 4; ++i) {
      const int row = i * 32 + lr32;
      bf16x8 y;
#pragma unroll
      for (int e = 0; e < 4; ++e) {
        y[e]     = (__bf16)fmaxf(0.f, fmaf((float)v[i][e],     s0[e], h0[e]));
        y[e + 4] = (__bf16)fmaxf(0.f, fmaf((float)v[i][e + 4], s1[e], h1[e]));
      }
      const int boff = row * 128 + ((cch * 16) ^ ((row & 7) << 4));
      *reinterpret_cast<bf16x8*>(reinterpret_cast<char*>(&As[buf][0]) + boff) = y;
    }
  };

  f32x4 acc[4][4] = {};
  const int fr = lane & 15, kc = lane >> 4;
  auto compute = [&](int buf) {
#pragma unroll
    for (int kk = 0; kk < 2; ++kk) {
      bf16x8 af[4], bfq[4];
#pragma unroll
      for (int mf = 0; mf < 4; ++mf) {
        const int row  = wr * 64 + mf * 16 + fr;
        const int boff = row * 128 + ((kk * 64 + kc * 16) ^ ((row & 7) << 4));
        af[mf] = *reinterpret_cast<const bf16x8*>(
            reinterpret_cast<const char*>(&As[buf][0]) + boff);
      }
#pragma unroll
      for (int nf = 0; nf < 4; ++nf) {
        const int row  = wc * 64 + nf * 16 + fr;
        const int boff = row * 128 + ((kk * 64 + kc * 16) ^ ((row & 7) << 4));
        bfq[nf] = *reinterpret_cast<const bf16x8*>(
            reinterpret_cast<const char*>(&Bs[buf][0]) + boff);
      }
#pragma unroll
      for (int mf = 0; mf < 4; ++mf)
#pragma unroll
        for (int nf = 0; nf < 4; ++nf)
          acc[mf][nf] = __builtin_amdgcn_mfma_f32_16x16x32_bf16(af[mf], bfq[nf], acc[mf][nf], 0, 0, 0);
    }
  };

  // prologue
  if (BN_A) {
    bf16x8 v0[4];
    load_a(v0, 0);
    bn_write(v0, 0, 0);
  } else {
    stage_a(0, 0);
  }
  stage_b(0, 0);
  __syncthreads();

  int buf = 0;
  for (int kt = 0; kt < 8; ++kt) {
    bf16x8 vn[4];
    if (kt < 7) {
      stage_b(buf ^ 1, kt + 1);
      if (!BN_A) stage_a(buf ^ 1, kt + 1);
      else       load_a(vn, kt + 1);
    }
    compute(buf);
    if (BN_A && kt < 7) bn_write(vn, buf ^ 1, kt + 1);
    __syncthreads();
    buf ^= 1;
  }

  // epilogue: C/D layout col=lane&15, row=(lane>>4)*4+j
  const int rq = (lane >> 4) * 4;
#pragma unroll
  for (int nf = 0; nf < 4; ++nf) {
    const int oc = n0 + wc * 64 + nf * 16 + fr;
    float s = 0.f, s2 = 0.f;
#pragma unroll
    for (int mf = 0; mf < 4; ++mf) {
      const int rb = m0 + wr * 64 + mf * 16 + rq;
      f32x4 v = acc[mf][nf];
#pragma unroll
      for (int j = 0; j < 4; ++j) {
        const float f = v[j];
        Co[(size_t)(rb + j) * RS_ + (size_t)h * C_ + oc] = (__bf16)f;
        s += f;
        s2 += f * f;
      }
    }
    s  += __shfl_xor(s, 16);  s  += __shfl_xor(s, 32);
    s2 += __shfl_xor(s2, 16); s2 += __shfl_xor(s2, 32);
    if (lane < 16) {
      atomicAdd(&sum_out[oc], s);
      atomicAdd(&sq_out[oc], s2);
    }
  }
}

// ---------------------------------------------------------------------------
// Final: out[n][o][h] = relu(a2[o]*t2[n][h][o] + c2[o] + x[n][o][h])
// t2 layout (N, H, C); a2/c2 computed per block from sum2/sq2.
// ---------------------------------------------------------------------------
__global__ __launch_bounds__(256) void k_finalize(const __bf16* __restrict__ t2,
                                                  const float* __restrict__ x,
                                                  const float* __restrict__ sum2,
                                                  const float* __restrict__ sq2,
                                                  const float* __restrict__ g2,
                                                  const float* __restrict__ b2,
                                                  float* __restrict__ out) {
  __shared__ float tile[64][65];
  __shared__ float a2s[64], c2s[64];
  const int n  = blockIdx.y;
  const int o0 = blockIdx.x * 64;
  const int t  = threadIdx.x;
  if (t < 64) {
    const int o = o0 + t;
    const float m    = sum2[o] * (1.f / 16384.f);
    const float var  = fmaxf(0.f, sq2[o] * (1.f / 16384.f) - m * m);
    const float a    = g2[o] * rsqrtf(var + 1e-5f);
    a2s[t] = a;
    c2s[t] = b2[o] - m * a;
  }
  const __bf16* tb = t2 + (size_t)n * RS_ + o0;
#pragma unroll
  for (int j = 0; j < 4; ++j) {
    const int hh = j * 16 + (t >> 4);
    const int ol = (t & 15) * 4;
    const bf16x4 v = *reinterpret_cast<const bf16x4*>(tb + (size_t)hh * 512 + ol);
#pragma unroll
    for (int e = 0; e < 4; ++e) tile[hh][ol + e] = (float)v[e];
  }
  __syncthreads();
  const int ol = t >> 2;
  const int hb = (t & 3) * 16;
  const int o  = o0 + ol;
  const float a = a2s[ol], c = c2s[ol];
  const float4* xp = reinterpret_cast<const float4*>(x + ((size_t)n * C_ + o) * H_ + hb);
  float4* op = reinterpret_cast<float4*>(out + ((size_t)n * C_ + o) * H_ + hb);
#pragma unroll
  for (int i4 = 0; i4 < 4; ++i4) {
    const float4 xv = xp[i4];
    float4 r;
    r.x = fmaxf(0.f, fmaf(a, tile[hb + i4 * 4 + 0][ol], c) + xv.x);
    r.y = fmaxf(0.f, fmaf(a, tile[hb + i4 * 4 + 1][ol], c) + xv.y);
    r.z = fmaxf(0.f, fmaf(a, tile[hb + i4 * 4 + 2][ol], c) + xv.z);
    r.w = fmaxf(0.f, fmaf(a, tile[hb + i4 * 4 + 3][ol], c) + xv.w);
    op[i4] = r;
  }
}

// ---------------------------------------------------------------------------
extern "C" void kernel_launch(void* const* d_in, const int* in_sizes, int n_in,
                              void* d_out, int out_size, void* d_ws, size_t ws_size,
                              hipStream_t stream) {
  const float* x  = (const float*)d_in[0];
  const float* w1 = (const float*)d_in[1];
  const float* g1 = (const float*)d_in[2];
  const float* b1 = (const float*)d_in[3];
  const float* w2 = (const float*)d_in[4];
  const float* g2 = (const float*)d_in[5];
  const float* b2 = (const float*)d_in[6];
  float* out = (float*)d_out;

  char* ws = (char*)d_ws;
  float* stats = (float*)ws;  // sum1, sq1, sum2, sq2
  float* sum1 = stats,        *sq1 = stats + 512;
  float* sum2 = stats + 1024, *sq2 = stats + 1536;
  const size_t MB = (size_t)1 << 20;
  __bf16* xT  = (__bf16*)(ws + 64 * 1024);
  __bf16* w1T = (__bf16*)(ws + 64 * 1024 + 16 * MB);
  __bf16* w2T = (__bf16*)(ws + 64 * 1024 + 48 * MB);
  __bf16* t1T = (__bf16*)(ws + 64 * 1024 + 80 * MB);
  __bf16* t2T = (__bf16*)(ws + 64 * 1024 + 96 * MB);

  k_prep<<<dim3(2, 1280), 256, 0, stream>>>(x, w1, w2, xT, w1T, w2T, stats);

  k_gemm<false><<<512, 256, 0, stream>>>(xT, w1T, t1T, nullptr, nullptr,
                                         nullptr, nullptr, sum1, sq1);
  k_gemm<true><<<512, 256, 0, stream>>>(t1T, w2T, t2T, sum1, sq1, g1, b1,
                                        sum2, sq2);

  k_finalize<<<dim3(8, 256), 256, 0, stream>>>(t2T, x, sum2, sq2, g2, b2, out);
}

// Round 5
// 105.192 us; speedup vs baseline: 1.0235x; 1.0235x over previous
//
#include <hip/hip_runtime.h>
#include <stdint.h>

typedef float  f32x4  __attribute__((ext_vector_type(4)));
typedef __bf16 bf16x8 __attribute__((ext_vector_type(8)));
typedef __bf16 bf16x4 __attribute__((ext_vector_type(4)));

#define N_ 256
#define C_ 512
#define H_ 64
#define RS_ 32768  // row stride in transposed tensors: H_*C_ elements

__device__ __forceinline__ uint32_t pack_bf16x2(float a, float b) {
  const uint16_t ua = __builtin_bit_cast(uint16_t, (__bf16)a);
  const uint16_t ub = __builtin_bit_cast(uint16_t, (__bf16)b);
  return (uint32_t)ua | ((uint32_t)ub << 16);
}

// ---------------------------------------------------------------------------
// Prep: (P, 512c, 64h) fp32 -> (P, 64h, 512c) bf16 for x, w1, w2.
// Block = (c-quarter 128c, p): reads 32 KB, writes 16 KB.
// LDS: u32 h-pair words, tile[128][32], pair-rotation swizzle keyed on c>>3:
//   word w of row c stored at ((w>>1)+(c>>3) & 15)*2 + (w&1)
// -> phase-2 reads (lanes vary in cb=c>>3) are conflict-free (broadcast pairs).
// 16 KB LDS -> 8 blocks/CU (full wave occupancy). Block (0,0) zeroes stats.
// ---------------------------------------------------------------------------
__global__ __launch_bounds__(256) void k_prep(const float* __restrict__ x,
                                              const float* __restrict__ w1,
                                              const float* __restrict__ w2,
                                              __bf16* __restrict__ xT,
                                              __bf16* __restrict__ w1T,
                                              __bf16* __restrict__ w2T,
                                              float* __restrict__ stats) {
  __shared__ uint32_t tile[128][32];
  const int t  = threadIdx.x;
  const int by = blockIdx.y;
  if (by == 0 && blockIdx.x == 0) {
#pragma unroll
    for (int i = 0; i < 8; ++i) stats[i * 256 + t] = 0.f;  // sum1,sq1,sum2,sq2
  }
  const float* src;
  __bf16* dst;
  int p;
  if (by < 256)      { src = x;  dst = xT;  p = by; }
  else if (by < 768) { src = w1; dst = w1T; p = by - 256; }
  else               { src = w2; dst = w2T; p = by - 768; }
  const int ch0 = blockIdx.x * 128;
  const float* sbase = src + ((size_t)p * 512 + ch0) * 64;

  // phase 1: load fp32 (64 B contiguous per lane-group), pack h-pairs to LDS
#pragma unroll
  for (int j = 0; j < 8; ++j) {
    const int fidx = j * 256 + t;
    const int c = fidx >> 4, hq = fidx & 15;
    const float4 v = *reinterpret_cast<const float4*>(sbase + c * 64 + hq * 4);
    const int wp = (hq + (c >> 3)) & 15;  // rotated pair slot
    uint2 pk;
    pk.x = pack_bf16x2(v.x, v.y);   // word 2hq   : h-pair (4hq,   4hq+1)
    pk.y = pack_bf16x2(v.z, v.w);   // word 2hq+1 : h-pair (4hq+2, 4hq+3)
    *reinterpret_cast<uint2*>(&tile[c][wp * 2]) = pk;
  }
  __syncthreads();

  // phase 2: gather 8 consecutive c-rows for one h; conflict-free reads
  // (16 lanes x distinct rotated pairs; even/odd-h lane pairs broadcast).
  __bf16* dbase = dst + (size_t)p * RS_ + ch0;
#pragma unroll
  for (int j = 0; j < 4; ++j) {
    const int ci = j * 256 + t;
    const int cb = ci & 15, h = ci >> 4;
    const int hm = h >> 1;                 // word index holding this h-pair
    const bool odd = (h & 1) != 0;
    uint32_t W[8];
#pragma unroll
    for (int i = 0; i < 8; ++i) {
      const int c = cb * 8 + i;
      const int w = (((hm >> 1) + cb) & 15) * 2 + (hm & 1);
      W[i] = tile[c][w];
    }
    uint4 o;
    uint32_t* op = reinterpret_cast<uint32_t*>(&o);
#pragma unroll
    for (int k = 0; k < 4; ++k) {
      const uint32_t wa = W[2 * k], wb = W[2 * k + 1];
      op[k] = odd ? ((wa >> 16) | (wb & 0xFFFF0000u))
                  : ((wa & 0xFFFFu) | (wb << 16));
    }
    *reinterpret_cast<uint4*>(dbase + (size_t)h * 512 + cb * 8) = o;
  }
}

// ---------------------------------------------------------------------------
// Batched NT GEMM: per h, C[256][512] = A[256][512] * B[512][512]^T  (bf16)
// Layouts: A (N,H,C), B (O,H,C), Co (N,H,C) -- row stride RS_=32768.
// 128x128 tile, 4 waves (2x2), BK=64, mfma_f32_16x16x32_bf16.
// XCD-aware swizzle: 512 blocks, each XCD owns 8 complete h slices.
// 2-phase double-buffered LDS staging; chunk-XOR swizzle via pre-swizzled
// global source (linear LDS dest). Epilogue: bf16 C + sum/sumsq atomics.
// BN_A: A gets y = relu(a1[k]*a + c1[k]) computed on the fly from sum1/sq1.
// ---------------------------------------------------------------------------
template <bool BN_A>
__global__ __launch_bounds__(256, 2) void k_gemm(
    const __bf16* __restrict__ A,
    const __bf16* __restrict__ B,
    __bf16* __restrict__ Co,
    const float* __restrict__ sum_in, const float* __restrict__ sq_in,
    const float* __restrict__ g, const float* __restrict__ bb,
    float* __restrict__ sum_out, float* __restrict__ sq_out) {
  const int wkid = (blockIdx.x & 7) * 64 + (blockIdx.x >> 3);
  const int h  = wkid >> 3;
  const int tm = (wkid >> 2) & 1, tn = wkid & 3;
  const int m0 = tm * 128, n0 = tn * 128;
  const __bf16* Ah = A + (size_t)m0 * RS_ + (size_t)h * C_;
  const __bf16* Bh = B + (size_t)n0 * RS_ + (size_t)h * C_;
  __shared__ __bf16 As[2][128 * 64];
  __shared__ __bf16 Bs[2][128 * 64];
  __shared__ float a_lds[512], c_lds[512];
  const int tid  = threadIdx.x;
  const int lane = tid & 63, wid = tid >> 6;
  const int wr = wid >> 1, wc = wid & 1;
  const int lrow8 = lane >> 3;
  const int swz   = (lane & 7) ^ lrow8;

  if (BN_A) {
#pragma unroll
    for (int ch = tid; ch < 512; ch += 256) {
      const float m    = sum_in[ch] * (1.f / 16384.f);
      const float var  = fmaxf(0.f, sq_in[ch] * (1.f / 16384.f) - m * m);
      const float aa   = g[ch] * rsqrtf(var + 1e-5f);
      a_lds[ch] = aa;
      c_lds[ch] = bb[ch] - m * aa;
    }
    __syncthreads();
  }

  auto stage_b = [&](int buf, int kt) {
#pragma unroll
    for (int i = 0; i < 4; ++i) {
      const int rbase = wid * 32 + i * 8;
      const __bf16* gb = Bh + (size_t)(rbase + lrow8) * RS_ + kt * 64 + swz * 8;
      __builtin_amdgcn_global_load_lds(
          (const __attribute__((address_space(1))) void*)gb,
          (__attribute__((address_space(3))) void*)(&Bs[buf][rbase * 64]), 16, 0, 0);
    }
  };
  auto stage_a = [&](int buf, int kt) {
#pragma unroll
    for (int i = 0; i < 4; ++i) {
      const int rbase = wid * 32 + i * 8;
      const __bf16* ga = Ah + (size_t)(rbase + lrow8) * RS_ + kt * 64 + swz * 8;
      __builtin_amdgcn_global_load_lds(
          (const __attribute__((address_space(1))) void*)ga,
          (__attribute__((address_space(3))) void*)(&As[buf][rbase * 64]), 16, 0, 0);
    }
  };
  const int lr32 = tid >> 3, cch = tid & 7;
  auto load_a = [&](bf16x8* v, int kt) {
#pragma unroll
    for (int i = 0; i < 4; ++i)
      v[i] = *reinterpret_cast<const bf16x8*>(
          Ah + (size_t)(i * 32 + lr32) * RS_ + kt * 64 + cch * 8);
  };
  auto bn_write = [&](const bf16x8* v, int buf, int kt) {
    const int cg = kt * 64 + cch * 8;
    const f32x4 s0 = *reinterpret_cast<const f32x4*>(&a_lds[cg]);
    const f32x4 s1 = *reinterpret_cast<const f32x4*>(&a_lds[cg + 4]);
    const f32x4 h0 = *reinterpret_cast<const f32x4*>(&c_lds[cg]);
    const f32x4 h1 = *reinterpret_cast<const f32x4*>(&c_lds[cg + 4]);
#pragma unroll
    for (int i = 0; i < 4; ++i) {
      const int row = i * 32 + lr32;
      bf16x8 y;
#pragma unroll
      for (int e = 0; e < 4; ++e) {
        y[e]     = (__bf16)fmaxf(0.f, fmaf((float)v[i][e],     s0[e], h0[e]));
        y[e + 4] = (__bf16)fmaxf(0.f, fmaf((float)v[i][e + 4], s1[e], h1[e]));
      }
      const int boff = row * 128 + ((cch * 16) ^ ((row & 7) << 4));
      *reinterpret_cast<bf16x8*>(reinterpret_cast<char*>(&As[buf][0]) + boff) = y;
    }
  };

  f32x4 acc[4][4] = {};
  const int fr = lane & 15, kc = lane >> 4;
  auto compute = [&](int buf) {
#pragma unroll
    for (int kk = 0; kk < 2; ++kk) {
      bf16x8 af[4], bfq[4];
#pragma unroll
      for (int mf = 0; mf < 4; ++mf) {
        const int row  = wr * 64 + mf * 16 + fr;
        const int boff = row * 128 + ((kk * 64 + kc * 16) ^ ((row & 7) << 4));
        af[mf] = *reinterpret_cast<const bf16x8*>(
            reinterpret_cast<const char*>(&As[buf][0]) + boff);
      }
#pragma unroll
      for (int nf = 0; nf < 4; ++nf) {
        const int row  = wc * 64 + nf * 16 + fr;
        const int boff = row * 128 + ((kk * 64 + kc * 16) ^ ((row & 7) << 4));
        bfq[nf] = *reinterpret_cast<const bf16x8*>(
            reinterpret_cast<const char*>(&Bs[buf][0]) + boff);
      }
#pragma unroll
      for (int mf = 0; mf < 4; ++mf)
#pragma unroll
        for (int nf = 0; nf < 4; ++nf)
          acc[mf][nf] = __builtin_amdgcn_mfma_f32_16x16x32_bf16(af[mf], bfq[nf], acc[mf][nf], 0, 0, 0);
    }
  };

  // prologue
  if (BN_A) {
    bf16x8 v0[4];
    load_a(v0, 0);
    bn_write(v0, 0, 0);
  } else {
    stage_a(0, 0);
  }
  stage_b(0, 0);
  __syncthreads();

  int buf = 0;
  for (int kt = 0; kt < 8; ++kt) {
    bf16x8 vn[4];
    if (kt < 7) {
      stage_b(buf ^ 1, kt + 1);
      if (!BN_A) stage_a(buf ^ 1, kt + 1);
      else       load_a(vn, kt + 1);
    }
    compute(buf);
    if (BN_A && kt < 7) bn_write(vn, buf ^ 1, kt + 1);
    __syncthreads();
    buf ^= 1;
  }

  // epilogue: C/D layout col=lane&15, row=(lane>>4)*4+j
  const int rq = (lane >> 4) * 4;
#pragma unroll
  for (int nf = 0; nf < 4; ++nf) {
    const int oc = n0 + wc * 64 + nf * 16 + fr;
    float s = 0.f, s2 = 0.f;
#pragma unroll
    for (int mf = 0; mf < 4; ++mf) {
      const int rb = m0 + wr * 64 + mf * 16 + rq;
      f32x4 v = acc[mf][nf];
#pragma unroll
      for (int j = 0; j < 4; ++j) {
        const float f = v[j];
        Co[(size_t)(rb + j) * RS_ + (size_t)h * C_ + oc] = (__bf16)f;
        s += f;
        s2 += f * f;
      }
    }
    s  += __shfl_xor(s, 16);  s  += __shfl_xor(s, 32);
    s2 += __shfl_xor(s2, 16); s2 += __shfl_xor(s2, 32);
    if (lane < 16) {
      atomicAdd(&sum_out[oc], s);
      atomicAdd(&sq_out[oc], s2);
    }
  }
}

// ---------------------------------------------------------------------------
// Final: out[n][o][h] = relu(a2[o]*t2[n][h][o] + c2[o] + x[n][o][h])
// t2 layout (N, H, C); a2/c2 computed per block from sum2/sq2.
// ---------------------------------------------------------------------------
__global__ __launch_bounds__(256) void k_finalize(const __bf16* __restrict__ t2,
                                                  const float* __restrict__ x,
                                                  const float* __restrict__ sum2,
                                                  const float* __restrict__ sq2,
                                                  const float* __restrict__ g2,
                                                  const float* __restrict__ b2,
                                                  float* __restrict__ out) {
  __shared__ float tile[64][65];
  __shared__ float a2s[64], c2s[64];
  const int n  = blockIdx.y;
  const int o0 = blockIdx.x * 64;
  const int t  = threadIdx.x;
  if (t < 64) {
    const int o = o0 + t;
    const float m    = sum2[o] * (1.f / 16384.f);
    const float var  = fmaxf(0.f, sq2[o] * (1.f / 16384.f) - m * m);
    const float a    = g2[o] * rsqrtf(var + 1e-5f);
    a2s[t] = a;
    c2s[t] = b2[o] - m * a;
  }
  const __bf16* tb = t2 + (size_t)n * RS_ + o0;
#pragma unroll
  for (int j = 0; j < 4; ++j) {
    const int hh = j * 16 + (t >> 4);
    const int ol = (t & 15) * 4;
    const bf16x4 v = *reinterpret_cast<const bf16x4*>(tb + (size_t)hh * 512 + ol);
#pragma unroll
    for (int e = 0; e < 4; ++e) tile[hh][ol + e] = (float)v[e];
  }
  __syncthreads();
  const int ol = t >> 2;
  const int hb = (t & 3) * 16;
  const int o  = o0 + ol;
  const float a = a2s[ol], c = c2s[ol];
  const float4* xp = reinterpret_cast<const float4*>(x + ((size_t)n * C_ + o) * H_ + hb);
  float4* op = reinterpret_cast<float4*>(out + ((size_t)n * C_ + o) * H_ + hb);
#pragma unroll
  for (int i4 = 0; i4 < 4; ++i4) {
    const float4 xv = xp[i4];
    float4 r;
    r.x = fmaxf(0.f, fmaf(a, tile[hb + i4 * 4 + 0][ol], c) + xv.x);
    r.y = fmaxf(0.f, fmaf(a, tile[hb + i4 * 4 + 1][ol], c) + xv.y);
    r.z = fmaxf(0.f, fmaf(a, tile[hb + i4 * 4 + 2][ol], c) + xv.z);
    r.w = fmaxf(0.f, fmaf(a, tile[hb + i4 * 4 + 3][ol], c) + xv.w);
    op[i4] = r;
  }
}

// ---------------------------------------------------------------------------
extern "C" void kernel_launch(void* const* d_in, const int* in_sizes, int n_in,
                              void* d_out, int out_size, void* d_ws, size_t ws_size,
                              hipStream_t stream) {
  const float* x  = (const float*)d_in[0];
  const float* w1 = (const float*)d_in[1];
  const float* g1 = (const float*)d_in[2];
  const float* b1 = (const float*)d_in[3];
  const float* w2 = (const float*)d_in[4];
  const float* g2 = (const float*)d_in[5];
  const float* b2 = (const float*)d_in[6];
  float* out = (float*)d_out;

  char* ws = (char*)d_ws;
  float* stats = (float*)ws;  // sum1, sq1, sum2, sq2
  float* sum1 = stats,        *sq1 = stats + 512;
  float* sum2 = stats + 1024, *sq2 = stats + 1536;
  const size_t MB = (size_t)1 << 20;
  __bf16* xT  = (__bf16*)(ws + 64 * 1024);
  __bf16* w1T = (__bf16*)(ws + 64 * 1024 + 16 * MB);
  __bf16* w2T = (__bf16*)(ws + 64 * 1024 + 48 * MB);
  __bf16* t1T = (__bf16*)(ws + 64 * 1024 + 80 * MB);
  __bf16* t2T = (__bf16*)(ws + 64 * 1024 + 96 * MB);

  k_prep<<<dim3(4, 1280), 256, 0, stream>>>(x, w1, w2, xT, w1T, w2T, stats);

  k_gemm<false><<<512, 256, 0, stream>>>(xT, w1T, t1T, nullptr, nullptr,
                                         nullptr, nullptr, sum1, sq1);
  k_gemm<true><<<512, 256, 0, stream>>>(t1T, w2T, t2T, sum1, sq1, g1, b1,
                                        sum2, sq2);

  k_finalize<<<dim3(8, 256), 256, 0, stream>>>(t2T, x, sum2, sq2, g2, b2, out);
}